// Round 18
// baseline (1763.830 us; speedup 1.0000x reference)
//
#include <hip/hip_runtime.h>
#include <hip/hip_bf16.h>
#include <cfloat>
#include <cmath>
#include <algorithm>

#define DEVI __device__ __forceinline__

typedef __attribute__((ext_vector_type(8))) short bf16x8;
typedef __attribute__((ext_vector_type(4))) float f32x4;

DEVI float eluf(float x){ return x > 0.f ? x : expm1f(x); }
DEVI unsigned encf(float v){ unsigned u = __float_as_uint(v); return (u & 0x80000000u) ? ~u : (u | 0x80000000u); }
DEVI float decf(unsigned u){ return (u & 0x80000000u) ? __uint_as_float(u & 0x7FFFFFFFu) : __uint_as_float(~u); }

DEVI unsigned short bfhi(float v){
  __hip_bfloat16 h = __float2bfloat16(v);
  return *reinterpret_cast<unsigned short*>(&h);
}
DEVI float bf2f(unsigned short u){
  __hip_bfloat16 h = *reinterpret_cast<__hip_bfloat16*>(&u);
  return __bfloat162float(h);
}

DEVI void basis3(const float* __restrict__ ea, int e, float fr[3], int k0[3]){
#pragma unroll
  for (int d = 0; d < 3; ++d){
    float p = ea[(size_t)e*3 + d];
    float v = fminf(fmaxf(p, 0.f), 1.f) * 2.f;
    float kf = fminf(floorf(v), 1.f);
    k0[d] = (int)kf;
    fr[d] = v - kf;
  }
}

// ---------------- CSR build ----------------
__global__ void k_degi(const int* __restrict__ ei, int E, int* __restrict__ deg){
  int e = blockIdx.x * 256 + threadIdx.x;
  if (e < E) atomicAdd(deg + ei[E + e], 1);
}

// parallel 3-phase exclusive scan over deg -> start/cursor (+ start[N])
__global__ __launch_bounds__(256) void k_scan1(const int* __restrict__ deg, int N, int* __restrict__ bsum){
  __shared__ int ls[256];
  const int t = threadIdx.x;
  const int base = blockIdx.x * 1024 + t * 4;
  int s = 0;
#pragma unroll
  for (int i = 0; i < 4; ++i){
    int idx = base + i;
    if (idx < N) s += deg[idx];
  }
  ls[t] = s;
  __syncthreads();
  for (int off = 128; off >= 1; off >>= 1){
    if (t < off) ls[t] += ls[t + off];
    __syncthreads();
  }
  if (t == 0) bsum[blockIdx.x] = ls[0];
}

__global__ __launch_bounds__(256) void k_scan2(int* __restrict__ bsum, int B1){
  __shared__ int ls[256];
  const int t = threadIdx.x;
  int v = (t < B1) ? bsum[t] : 0;
  ls[t] = v;
  __syncthreads();
  for (int off = 1; off < 256; off <<= 1){
    int u = (t >= off) ? ls[t - off] : 0;
    __syncthreads();
    ls[t] += u;
    __syncthreads();
  }
  if (t < B1) bsum[t] = ls[t] - v;   // exclusive
}

__global__ __launch_bounds__(256) void k_scan3(const int* __restrict__ deg, int N,
                                               const int* __restrict__ bsum,
                                               int* __restrict__ start, int* __restrict__ cursor){
  __shared__ int ls[256];
  const int t = threadIdx.x;
  const int base = blockIdx.x * 1024 + t * 4;
  int v[4]; int tsum = 0;
#pragma unroll
  for (int i = 0; i < 4; ++i){
    int idx = base + i;
    v[i] = (idx < N) ? deg[idx] : 0;
    tsum += v[i];
  }
  ls[t] = tsum;
  __syncthreads();
  for (int off = 1; off < 256; off <<= 1){
    int u = (t >= off) ? ls[t - off] : 0;
    __syncthreads();
    ls[t] += u;
    __syncthreads();
  }
  int run = bsum[blockIdx.x] + ls[t] - tsum;
#pragma unroll
  for (int i = 0; i < 4; ++i){
    int idx = base + i;
    if (idx < N){
      start[idx] = run; cursor[idx] = run;
      run += v[i];
      if (idx == N - 1) start[N] = run;
    }
  }
}

__global__ void k_perm(const int* __restrict__ ei, int E, int* __restrict__ cursor, int* __restrict__ perm){
  int e = blockIdx.x * 256 + threadIdx.x;
  if (e < E){
    int p = atomicAdd(cursor + ei[E + e], 1);
    perm[p] = e;
  }
}

// ---------------- phase A: compact per-edge basis (fr0,fr1,fr2, k0packed), CSR order ----------------
__global__ void k_prep(const int* __restrict__ ei, const float* __restrict__ ea, int E,
                       const int* __restrict__ perm, int* __restrict__ srcs,
                       float4* __restrict__ bas){
  int j = blockIdx.x * 256 + threadIdx.x;
  if (j >= E) return;
  int e = perm[j];
  srcs[j] = ei[e];
  float fr[3]; int k0[3];
  basis3(ea, e, fr, k0);
  int kp = k0[0] | (k0[1] << 1) | (k0[2] << 2);
  bas[j] = make_float4(fr[0], fr[1], fr[2], __int_as_float(kp));
}

// ---------------- per-edge 8-tap trilinear accumulate: wave-uniform switch, static indices ----------------
// 17 VALU/edge: 3 sub + 2 mul + 4 mul + 8 fma. kp is identical across lanes -> scalar branch.
#define TAPX(A,B,C) \
    acc[(A)*9+(B)*3+(C)]       = fmaf(u00, g2, acc[(A)*9+(B)*3+(C)]); \
    acc[(A)*9+(B)*3+(C)+1]     = fmaf(u00, f2, acc[(A)*9+(B)*3+(C)+1]); \
    acc[(A)*9+((B)+1)*3+(C)]   = fmaf(u01, g2, acc[(A)*9+((B)+1)*3+(C)]); \
    acc[(A)*9+((B)+1)*3+(C)+1] = fmaf(u01, f2, acc[(A)*9+((B)+1)*3+(C)+1]); \
    acc[((A)+1)*9+(B)*3+(C)]       = fmaf(u10, g2, acc[((A)+1)*9+(B)*3+(C)]); \
    acc[((A)+1)*9+(B)*3+(C)+1]     = fmaf(u10, f2, acc[((A)+1)*9+(B)*3+(C)+1]); \
    acc[((A)+1)*9+((B)+1)*3+(C)]   = fmaf(u11, g2, acc[((A)+1)*9+((B)+1)*3+(C)]); \
    acc[((A)+1)*9+((B)+1)*3+(C)+1] = fmaf(u11, f2, acc[((A)+1)*9+((B)+1)*3+(C)+1]);

// ---------------- shared edge accumulation: 2-stage software pipeline + 8-tap compute ----------------
template<int FIN>
DEVI void edge_accum(const float* __restrict__ x, const int* __restrict__ srcs,
                     const float4* __restrict__ bas, int j0, int j1, int off, float acc[27]){
  if (j0 >= j1) return;
  auto ACCT = [&](const float4& Bv, float xv){
    int kp = __builtin_amdgcn_readfirstlane(__float_as_int(Bv.w));
    float f0 = Bv.x, f1 = Bv.y, f2 = Bv.z;
    float g0 = 1.f - f0, g1 = 1.f - f1, g2 = 1.f - f2;
    float t0 = g0 * xv, t1 = f0 * xv;
    float u00 = t0 * g1, u01 = t0 * f1, u10 = t1 * g1, u11 = t1 * f1;
    switch (kp){
      case 0: TAPX(0,0,0); break;
      case 1: TAPX(1,0,0); break;
      case 2: TAPX(0,1,0); break;
      case 3: TAPX(1,1,0); break;
      case 4: TAPX(0,0,1); break;
      case 5: TAPX(1,0,1); break;
      case 6: TAPX(0,1,1); break;
      default: TAPX(1,1,1); break;
    }
  };
  const int F = (j1 - j0) >> 2;        // full groups of 4
  const int r = (j1 - j0) & 3;         // tail edges
  float4 Ba[4], Bb[4], Bc[4];
  int sb[4], sc[4];
  float xa[4], xb[4];
  auto cl = [&](int j){ return j < j1 ? j : j1 - 1; };
  {
    int s0[4];
#pragma unroll
    for (int e = 0; e < 4; ++e){ int j = cl(j0 + e); Ba[e] = bas[j]; s0[e] = srcs[j]; }
#pragma unroll
    for (int e = 0; e < 4; ++e) xa[e] = x[(size_t)s0[e] * FIN + off];
#pragma unroll
    for (int e = 0; e < 4; ++e){ int j = cl(j0 + 4 + e); Bb[e] = bas[j]; sb[e] = srcs[j]; }
  }
  for (int g = 0; g < F; ++g){
    // x loads for group g+1 (srcs already resident)
#pragma unroll
    for (int e = 0; e < 4; ++e) xb[e] = x[(size_t)sb[e] * FIN + off];
    // bas+srcs for group g+2
#pragma unroll
    for (int e = 0; e < 4; ++e){ int j = cl(j0 + (g + 2) * 4 + e); Bc[e] = bas[j]; sc[e] = srcs[j]; }
    // compute group g (exactly 4 real edges)
#pragma unroll
    for (int e = 0; e < 4; ++e) ACCT(Ba[e], xa[e]);
    // rotate stages
#pragma unroll
    for (int e = 0; e < 4; ++e){
      Ba[e] = Bb[e]; xa[e] = xb[e];
      Bb[e] = Bc[e]; sb[e] = sc[e];
    }
  }
  // tail: 0..3 real edges staged in Ba/xa
  if (r > 0) ACCT(Ba[0], xa[0]);
  if (r > 1) ACCT(Ba[1], xa[1]);
  if (r > 2) ACCT(Ba[2], xa[2]);
}

// ---------------- phase B gather ----------------
template<int FIN>
__global__ __launch_bounds__(256) void k_gather(
    const float* __restrict__ x, const int* __restrict__ start,
    const int* __restrict__ srcs, const float4* __restrict__ bas,
    unsigned short* __restrict__ Sh, int n0, int n1){
  constexpr int S = FIN / 64;
  constexpr int NPB = 4 / S;
  constexpr int KAUG = 28 * FIN;
  const int wv = threadIdx.x >> 6;
  const int lane = threadIdx.x & 63;
  const int n = n0 + blockIdx.x * NPB + wv / S;
  const int slice = wv % S;
  if (n >= n1) return;
  const int j0 = __builtin_amdgcn_readfirstlane(start[n]);
  const int j1 = __builtin_amdgcn_readfirstlane(start[n + 1]);
  const int off = slice * 64 + lane;

  float acc[27];
#pragma unroll
  for (int k = 0; k < 27; ++k) acc[k] = 0.f;
  edge_accum<FIN>(x, srcs, bas, j0, j1, off, acc);
  const float invd = 1.f / fmaxf((float)(j1 - j0), 1.f);
  const size_t rb = (size_t)(n - n0) * KAUG + off;
#pragma unroll
  for (int k = 0; k < 27; ++k)
    Sh[rb + (size_t)k * FIN] = bfhi(acc[k] * invd);
  Sh[rb + (size_t)27 * FIN] = bfhi(x[(size_t)n * FIN + off]);
}

// ---------------- W conversion: W_aug^T -> bf16 hi/lo [FOUT][KAUG] (tiled transpose) ----------------
template<int FIN, int FOUT>
__global__ __launch_bounds__(256) void k_cvtW(const float* __restrict__ W, const float* __restrict__ root,
                                              unsigned short* __restrict__ wh, unsigned short* __restrict__ wl){
  constexpr int KA = 28 * FIN;
  __shared__ unsigned short th[64][66];
  __shared__ unsigned short tl[64][66];
  const int kk0 = blockIdx.x * 64, o0 = blockIdx.y * 64;
  const int tx = threadIdx.x & 63, ty = threadIdx.x >> 6;
  for (int i = ty; i < 64; i += 4){
    int kk = kk0 + i;
    float v = (kk < 27 * FIN) ? W[(size_t)kk * FOUT + o0 + tx]
                              : root[(size_t)(kk - 27 * FIN) * FOUT + o0 + tx];
    unsigned short h = bfhi(v);
    th[i][tx] = h;
    tl[i][tx] = bfhi(v - bf2f(h));
  }
  __syncthreads();
  for (int i = ty; i < 64; i += 4){
    wh[(size_t)(o0 + i) * KA + kk0 + tx] = th[tx][i];
    wl[(size_t)(o0 + i) * KA + kk0 + tx] = tl[tx][i];
  }
}

// ---------------- split-K MFMA conv GEMM, BM=128 x BN=128: P[z] = S @ (Wh + Wl) ----------------
template<int KAUG, int FOUT, int KS>
__global__ __launch_bounds__(256) void k_mfmaconv(
    const unsigned short* __restrict__ Sh,
    const unsigned short* __restrict__ Wh, const unsigned short* __restrict__ Wl,
    float* __restrict__ P, int cn){
  constexpr int KSTEPS = KAUG / 32 / KS;
  __shared__ unsigned short Ah[128][40];
  __shared__ unsigned short Bh[128][40];
  __shared__ unsigned short Bl[128][40];
  const int t = threadIdx.x;
  const int lane = t & 63, wv = t >> 6;
  const int wm = (wv >> 1) * 64, wn = (wv & 1) * 64;
  const int mb = blockIdx.y * 128;
  const int ob = blockIdx.x * 128;
  const int kbase = blockIdx.z * KSTEPS * 32;
  const int l16 = lane & 15, l4 = lane >> 4;
  f32x4 acc[4][4] = {};

  for (int ks = 0; ks < KSTEPS; ++ks){
#pragma unroll
    for (int i = 0; i < 2; ++i){
      int slot = t + i * 256;
      int row = slot >> 2, col = (slot & 3) * 8;
      uint4 va = make_uint4(0, 0, 0, 0);
      if (mb + row < cn)
        va = *reinterpret_cast<const uint4*>(Sh + (size_t)(mb + row) * KAUG + kbase + ks * 32 + col);
      *reinterpret_cast<uint4*>(&Ah[row][col]) = va;
      *reinterpret_cast<uint4*>(&Bh[row][col]) =
        *reinterpret_cast<const uint4*>(Wh + (size_t)(ob + row) * KAUG + kbase + ks * 32 + col);
      *reinterpret_cast<uint4*>(&Bl[row][col]) =
        *reinterpret_cast<const uint4*>(Wl + (size_t)(ob + row) * KAUG + kbase + ks * 32 + col);
    }
    __syncthreads();
    bf16x8 ah[4], bh[4], bl[4];
#pragma unroll
    for (int m = 0; m < 4; ++m)
      ah[m] = *reinterpret_cast<const bf16x8*>(&Ah[wm + m * 16 + l16][l4 * 8]);
#pragma unroll
    for (int n = 0; n < 4; ++n){
      bh[n] = *reinterpret_cast<const bf16x8*>(&Bh[wn + n * 16 + l16][l4 * 8]);
      bl[n] = *reinterpret_cast<const bf16x8*>(&Bl[wn + n * 16 + l16][l4 * 8]);
    }
#pragma unroll
    for (int m = 0; m < 4; ++m)
#pragma unroll
      for (int n = 0; n < 4; ++n){
        acc[m][n] = __builtin_amdgcn_mfma_f32_16x16x32_bf16(ah[m], bh[n], acc[m][n], 0, 0, 0);
        acc[m][n] = __builtin_amdgcn_mfma_f32_16x16x32_bf16(ah[m], bl[n], acc[m][n], 0, 0, 0);
      }
    __syncthreads();
  }
  float* Pz = P + (size_t)blockIdx.z * cn * FOUT;
#pragma unroll
  for (int n = 0; n < 4; ++n){
    int col = ob + wn + n * 16 + l16;
#pragma unroll
    for (int m = 0; m < 4; ++m){
#pragma unroll
      for (int r = 0; r < 4; ++r){
        int gr = mb + wm + m * 16 + l4 * 4 + r;
        if (gr < cn) Pz[(size_t)gr * FOUT + col] = acc[m][n][r];
      }
    }
  }
}

// ---------------- split-K reduce + bias + elu ----------------
template<int FOUT, int KS>
__global__ __launch_bounds__(256) void k_red(const float* __restrict__ P, const float* __restrict__ bias,
                                             float* __restrict__ H, int cn, int n0){
  const size_t tot4 = (size_t)cn * FOUT / 4;
  const size_t zs = tot4;
  float* Hb = H + (size_t)n0 * FOUT;
  for (size_t i = (size_t)blockIdx.x * 256 + threadIdx.x; i < tot4; i += (size_t)gridDim.x * 256){
    f32x4 s = reinterpret_cast<const f32x4*>(P)[i];
#pragma unroll
    for (int z = 1; z < KS; ++z){
      f32x4 v = reinterpret_cast<const f32x4*>(P)[(size_t)z * zs + i];
      s[0] += v[0]; s[1] += v[1]; s[2] += v[2]; s[3] += v[3];
    }
    int col = (int)((i * 4) % FOUT);
    float4 b = *reinterpret_cast<const float4*>(bias + col);
    f32x4 o;
    o[0] = eluf(s[0] + b.x); o[1] = eluf(s[1] + b.y);
    o[2] = eluf(s[2] + b.z); o[3] = eluf(s[3] + b.w);
    reinterpret_cast<f32x4*>(Hb)[i] = o;
  }
}

// ---------------- fused level-1 (Fin=1, deg==8, dst sorted by construction) ----------------
__global__ __launch_bounds__(256) void k_l1(const int* __restrict__ ei, const float* __restrict__ ea,
    const float* __restrict__ x, const float* __restrict__ W, const float* __restrict__ root,
    const float* __restrict__ bias, float* __restrict__ H){
  __shared__ float sl[256 * 27];
  const int t = threadIdx.x;
  const int nb = blockIdx.x * 256;
  const int n = nb + t;
  float acc[27];
#pragma unroll
  for (int k = 0; k < 27; ++k) acc[k] = 0.f;
  for (int j = 0; j < 8; ++j){
    int e = n * 8 + j;
    int src = ei[e];
    float fr[3]; int k0[3];
    basis3(ea, e, fr, k0);
    float xv = x[src];
    float u[3][3];
#pragma unroll
    for (int d = 0; d < 3; ++d){
      bool z = (k0[d] == 0);
      float f = fr[d];
      u[d][0] = z ? 1.f - f : 0.f;
      u[d][1] = z ? f : 1.f - f;
      u[d][2] = z ? 0.f : f;
    }
    float ta[3] = {u[0][0] * xv, u[0][1] * xv, u[0][2] * xv};
#pragma unroll
    for (int a = 0; a < 3; ++a)
#pragma unroll
      for (int b = 0; b < 3; ++b){
        float p = ta[a] * u[1][b];
#pragma unroll
        for (int c = 0; c < 3; ++c)
          acc[(a * 3 + b) * 3 + c] = fmaf(p, u[2][c], acc[(a * 3 + b) * 3 + c]);
      }
  }
#pragma unroll
  for (int k = 0; k < 27; ++k) sl[t * 27 + k] = acc[k];
  const int o = t & 63, grp = t >> 6;
  float wr[27];
#pragma unroll
  for (int k = 0; k < 27; ++k) wr[k] = W[k * 64 + o];
  const float ro = root[o], bo = bias[o];
  __syncthreads();
  for (int r = 0; r < 64; ++r){
    int m = grp * 64 + r;
    float a = 0.f;
#pragma unroll
    for (int k = 0; k < 27; ++k) a = fmaf(sl[m * 27 + k], wr[k], a);
    H[(size_t)(nb + m) * 64 + o] = eluf(a * 0.125f + x[nb + m] * ro + bo);
  }
}

// ---------------- BN stats: two-stage, register accumulation, no atomics ----------------
template<int F>
__global__ __launch_bounds__(256) void k_bnstat(const float* __restrict__ h, int N, float* __restrict__ partial){
  constexpr int FE = (F < 256) ? F : 256;
  constexpr int TPC = 256 / FE;
  constexpr int CPT = (F > 256) ? (F / 256) : 1;
  constexpr int LOGFE = (FE == 64) ? 6 : (FE == 128) ? 7 : 8;
  const int t = threadIdx.x;
  const int col = t & (FE - 1);
  const int ro = t >> LOGFE;
  float s[CPT], q[CPT];
#pragma unroll
  for (int c = 0; c < CPT; ++c){ s[c] = 0.f; q[c] = 0.f; }
  for (int r = blockIdx.x * TPC + ro; r < N; r += gridDim.x * TPC){
#pragma unroll
    for (int c = 0; c < CPT; ++c){
      float v = h[(size_t)r * F + col + c * 256];
      s[c] += v; q[c] += v * v;
    }
  }
  float* pb = partial + (size_t)blockIdx.x * 2 * F;
  __shared__ float ls[2 * FE];
  if (TPC == 1){
#pragma unroll
    for (int c = 0; c < CPT; ++c){
      pb[col + c * 256] = s[c];
      pb[F + col + c * 256] = q[c];
    }
  } else {
    for (int p = 0; p < TPC; ++p){
      if (ro == p){
        if (p == 0){ ls[col] = s[0]; ls[FE + col] = q[0]; }
        else { ls[col] += s[0]; ls[FE + col] += q[0]; }
      }
      __syncthreads();
    }
    if (t < 2 * F) pb[t] = ls[t];
  }
}

__global__ void k_bnfin2(const float* __restrict__ partial, int G, const float* __restrict__ gamma,
                         const float* __restrict__ beta, float invn, int F, float* __restrict__ ss){
  int f = blockIdx.x * 256 + threadIdx.x;
  if (f >= F) return;
  float s = 0.f, q = 0.f;
  for (int g = 0; g < G; ++g){
    s += partial[(size_t)g * 2 * F + f];
    q += partial[(size_t)g * 2 * F + F + f];
  }
  float mu = s * invn;
  float var = q * invn - mu * mu;
  float sc = gamma[f] * rsqrtf(var + 1e-5f);
  ss[f] = sc;
  ss[F + f] = beta[f] - mu * sc;
}

__global__ void k_fillenc(unsigned* __restrict__ p, long long n){
  for (long long i = (long long)blockIdx.x * 256 + threadIdx.x; i < n; i += (long long)gridDim.x * 256)
    p[i] = 0x00800000u;
}

template<int F>
__global__ __launch_bounds__(256) void k_pool(const float* __restrict__ h, const float* __restrict__ ss,
                     const int* __restrict__ cl, unsigned* __restrict__ enc,
                     int* __restrict__ cnt, long long total){
  constexpr int LOG = (F == 64) ? 6 : (F == 128) ? 7 : (F == 256) ? 8 : 9;
  for (long long idx = (long long)blockIdx.x * 256 + threadIdx.x; idx < total; idx += (long long)gridDim.x * 256){
    int f = (int)(idx & (F - 1));
    int m = (int)(idx >> LOG);
    int c = cl[m];
    float v = fmaf(h[idx], ss[f], ss[F + f]);
    atomicMax(enc + (size_t)c * F + f, encf(v));
    if (f == 0) atomicAdd(cnt + c, 1);
  }
}

__global__ void k_dec(unsigned* __restrict__ enc, const int* __restrict__ cnt, int logF, long long total){
  for (long long idx = (long long)blockIdx.x * 256 + threadIdx.x; idx < total; idx += (long long)gridDim.x * 256){
    int sg = (int)(idx >> logF);
    float v = (cnt[sg] > 0) ? decf(enc[idx]) : 0.f;
    reinterpret_cast<float*>(enc)[idx] = v;
  }
}

// ---------------- FC head ----------------
__global__ __launch_bounds__(256) void k_fc1p(const float* __restrict__ X, const float* __restrict__ Wt,
                       float* __restrict__ outacc){
  __shared__ float Xs[8][512];
  __shared__ float4 red[16][16];
  const int t = threadIdx.x;
  const int o0 = blockIdx.x * 64;
  const int kbase = blockIdx.y * 512;
  for (int i = t; i < 8 * 128; i += 256){
    int g = i >> 7, u = i & 127;
    reinterpret_cast<float4*>(Xs[g])[u] =
      *reinterpret_cast<const float4*>(X + (size_t)g * 32768 + kbase + u * 4);
  }
  __syncthreads();
  const int ol = t & 15;
  const int kr = t >> 4;
  float4 acc[8];
#pragma unroll
  for (int g = 0; g < 8; ++g) acc[g] = make_float4(0.f, 0.f, 0.f, 0.f);
#pragma unroll 4
  for (int kk = kr; kk < 512; kk += 16){
    float4 wv = *reinterpret_cast<const float4*>(Wt + (size_t)(kbase + kk) * 1024 + o0 + ol * 4);
#pragma unroll
    for (int g = 0; g < 8; ++g){
      float xv = Xs[g][kk];
      acc[g].x = fmaf(xv, wv.x, acc[g].x);
      acc[g].y = fmaf(xv, wv.y, acc[g].y);
      acc[g].z = fmaf(xv, wv.z, acc[g].z);
      acc[g].w = fmaf(xv, wv.w, acc[g].w);
    }
  }
  for (int g = 0; g < 8; ++g){
    red[kr][ol] = acc[g];
    __syncthreads();
    if (kr == 0){
      float4 s = red[0][ol];
#pragma unroll
      for (int p = 1; p < 16; ++p){
        float4 v = red[p][ol];
        s.x += v.x; s.y += v.y; s.z += v.z; s.w += v.w;
      }
      atomicAdd(&outacc[(size_t)g * 1024 + o0 + ol * 4 + 0], s.x);
      atomicAdd(&outacc[(size_t)g * 1024 + o0 + ol * 4 + 1], s.y);
      atomicAdd(&outacc[(size_t)g * 1024 + o0 + ol * 4 + 2], s.z);
      atomicAdd(&outacc[(size_t)g * 1024 + o0 + ol * 4 + 3], s.w);
    }
    __syncthreads();
  }
}

__global__ void k_fc1fin(float* __restrict__ o, const float* __restrict__ b){
  int i = blockIdx.x * 256 + threadIdx.x;
  if (i < 8192) o[i] = eluf(o[i] + b[i & 1023]);
}

__global__ __launch_bounds__(256) void k_fc2(const float* __restrict__ h, const float* __restrict__ W2,
                      const float* __restrict__ b2, float* __restrict__ out){
  const int g = blockIdx.x;
  const int o = threadIdx.x & 1;
  const int kk = threadIdx.x >> 1;
  float acc = 0.f;
  for (int k = kk; k < 1024; k += 128) acc = fmaf(h[(size_t)g * 1024 + k], W2[(size_t)k * 2 + o], acc);
  __shared__ float ls[256];
  ls[threadIdx.x] = acc;
  __syncthreads();
  for (int st = 64; st >= 1; st >>= 1){
    if (kk < st) ls[kk * 2 + o] += ls[(kk + st) * 2 + o];
    __syncthreads();
  }
  if (kk == 0) out[g * 2 + o] = ls[o] + b2[o];
}

// ---------------- per-level driver ----------------
template<int FIN, int FOUT, int KS>
static void run_level(const float* xin, int N, const int* ei, int E, const float* ea,
                      const float* W, const float* root, const float* bias,
                      const float* gamma, const float* beta,
                      const int* cl, int npool, int logF,
                      float* h, float* pout, int* degi, int* startb, int* cursor, int* perm,
                      int* srcs, float4* bas, int* bsum,
                      int* cnt, float* bnss,
                      unsigned short* wth, unsigned short* wtl, float* pbuf,
                      unsigned short* sbuf16, size_t sbytes, hipStream_t stream){
  constexpr int KAUG = 28 * FIN;
  hipMemsetAsync(degi, 0, (size_t)N * 4, stream);
  k_degi<<<(E + 255) / 256, 256, 0, stream>>>(ei, E, degi);
  int B1 = (N + 1023) / 1024;
  k_scan1<<<B1, 256, 0, stream>>>(degi, N, bsum);
  k_scan2<<<1, 256, 0, stream>>>(bsum, B1);
  k_scan3<<<B1, 256, 0, stream>>>(degi, N, bsum, startb, cursor);
  k_perm<<<(E + 255) / 256, 256, 0, stream>>>(ei, E, cursor, perm);
  k_prep<<<(E + 255) / 256, 256, 0, stream>>>(ei, ea, E, perm, srcs, bas);
  k_cvtW<FIN, FOUT><<<dim3(KAUG / 64, FOUT / 64), 256, 0, stream>>>(W, root, wth, wtl);
  const size_t perNode = (size_t)KAUG * 2;   // hi plane only, 2B
  long long cN = (long long)(sbytes / perNode);
  int chunk = (int)std::min<long long>((long long)N, std::max<long long>(cN, 1));
  constexpr int NPB = 256 / FIN;
  unsigned short* Sh = sbuf16;
  for (int n0 = 0; n0 < N; n0 += chunk){
    int n1e = std::min(N, n0 + chunk);
    int cn = n1e - n0;
    k_gather<FIN><<<(cn + NPB - 1) / NPB, 256, 0, stream>>>(xin, startb, srcs, bas, Sh, n0, n1e);
    dim3 g(FOUT / 128, (cn + 127) / 128, KS);
    k_mfmaconv<KAUG, FOUT, KS><<<g, 256, 0, stream>>>(Sh, wth, wtl, pbuf, cn);
    int rb = (int)std::min<long long>(2048, ((long long)cn * FOUT / 4 + 255) / 256);
    k_red<FOUT, KS><<<rb, 256, 0, stream>>>(pbuf, bias, h, cn, n0);
  }
  k_bnstat<FOUT><<<256, 256, 0, stream>>>(h, N, pbuf);
  k_bnfin2<<<(FOUT + 255) / 256, 256, 0, stream>>>(pbuf, 256, gamma, beta, 1.f / (float)N, FOUT, bnss);
  long long tot = (long long)N * FOUT;
  int nb = (int)std::min<long long>(2048, (tot + 255) / 256);
  long long ptot = (long long)npool * FOUT;
  int pb = (int)std::min<long long>(2048, (ptot + 255) / 256);
  k_fillenc<<<pb, 256, 0, stream>>>((unsigned*)pout, ptot);
  hipMemsetAsync(cnt, 0, (size_t)npool * 4, stream);
  k_pool<FOUT><<<nb, 256, 0, stream>>>(h, bnss, cl, (unsigned*)pout, cnt, tot);
  k_dec<<<pb, 256, 0, stream>>>((unsigned*)pout, cnt, logF, ptot);
}

extern "C" void kernel_launch(void* const* d_in, const int* in_sizes, int n_in,
                              void* d_out, int out_size, void* d_ws, size_t ws_size,
                              hipStream_t stream){
  const float* x1  = (const float*)d_in[0];
  const int*   ei1 = (const int*)d_in[1];
  const float* ea1 = (const float*)d_in[2];
  const int*   cl1 = (const int*)d_in[3];
  const int*   ei2 = (const int*)d_in[4];
  const float* ea2 = (const float*)d_in[5];
  const int*   cl2 = (const int*)d_in[6];
  const int*   ei3 = (const int*)d_in[7];
  const float* ea3 = (const float*)d_in[8];
  const int*   cl3 = (const int*)d_in[9];
  const int*   ei4 = (const int*)d_in[10];
  const float* ea4 = (const float*)d_in[11];
  const int*   cl4 = (const int*)d_in[12];
  const float* W1 = (const float*)d_in[13]; const float* r1 = (const float*)d_in[14];
  const float* b1 = (const float*)d_in[15]; const float* g1 = (const float*)d_in[16]; const float* be1 = (const float*)d_in[17];
  const float* W2 = (const float*)d_in[18]; const float* r2 = (const float*)d_in[19];
  const float* b2 = (const float*)d_in[20]; const float* g2 = (const float*)d_in[21]; const float* be2 = (const float*)d_in[22];
  const float* W3 = (const float*)d_in[23]; const float* r3 = (const float*)d_in[24];
  const float* b3 = (const float*)d_in[25]; const float* g3 = (const float*)d_in[26]; const float* be3 = (const float*)d_in[27];
  const float* W4 = (const float*)d_in[28]; const float* r4 = (const float*)d_in[29];
  const float* b4 = (const float*)d_in[30]; const float* g4 = (const float*)d_in[31]; const float* be4 = (const float*)d_in[32];
  const float* fw1 = (const float*)d_in[33]; const float* fb1 = (const float*)d_in[34];
  const float* fw2 = (const float*)d_in[35]; const float* fb2 = (const float*)d_in[36];

  const int N1 = in_sizes[0];
  const int E1 = in_sizes[1] / 2;
  const int N2 = in_sizes[6];
  const int E2 = in_sizes[4] / 2;
  const int N3 = in_sizes[9];
  const int E3 = in_sizes[7] / 2;
  const int N4 = in_sizes[12];
  const int E4 = in_sizes[10] / 2;
  (void)E1;

  char* base = (char*)d_ws;
  size_t off = 0;
  auto alloc = [&](size_t bytes) -> char* {
    char* p = base + off;
    off += (bytes + 255) & ~(size_t)255;
    return p;
  };
  size_t hbytes = 4 * std::max(std::max((size_t)N1 * 64, (size_t)N2 * 128),
                               std::max((size_t)N3 * 256, (size_t)N4 * 512));
  size_t pbytes = 4 * std::max(std::max((size_t)N2 * 64, (size_t)N3 * 128),
                               std::max((size_t)N4 * 256, (size_t)512 * 512));
  float* harena = (float*)alloc(hbytes);
  float* parena = (float*)alloc(pbytes);
  float* fco = (float*)alloc(8 * 1024 * 4);
  int Nmax = std::max(std::max(N1, N2), std::max(N3, N4));
  int Emax = std::max(std::max(E2, E3), E4);
  int* degi = (int*)alloc((size_t)Nmax * 4);
  int* startb = (int*)alloc(((size_t)Nmax + 1) * 4);
  int* cursor = (int*)alloc((size_t)Nmax * 4);
  int* perm = (int*)alloc((size_t)Emax * 4);
  int* srcs = (int*)alloc((size_t)Emax * 4);
  float4* bas = (float4*)alloc((size_t)Emax * 16);
  int* bsum = (int*)alloc(256 * 4);
  int* cnt = (int*)alloc((size_t)std::max(std::max(N2, N3), std::max(N4, 512)) * 4);
  float* bnss = (float*)alloc(2 * 512 * 4);
  unsigned short* wth = (unsigned short*)alloc((size_t)512 * 7168 * 2);
  unsigned short* wtl = (unsigned short*)alloc((size_t)512 * 7168 * 2);
  size_t pmax = std::max((size_t)2 * N2 * 128, std::max((size_t)4 * N3 * 256, (size_t)8 * N4 * 512));
  pmax = std::max(pmax, (size_t)256 * 2 * 512);   // bnstat partials
  float* pbuf = (float*)alloc(pmax * 4);
  unsigned short* sbuf16 = (unsigned short*)(base + off);
  size_t sbytes = ws_size > off ? ws_size - off : 0;

  // ---- level 1 (fused; Fin=1, deg==8, dst sorted by construction) ----
  {
    k_l1<<<N1 / 256, 256, 0, stream>>>(ei1, ea1, x1, W1, r1, b1, harena);
    k_bnstat<64><<<256, 256, 0, stream>>>(harena, N1, pbuf);
    k_bnfin2<<<1, 256, 0, stream>>>(pbuf, 256, g1, be1, 1.f / (float)N1, 64, bnss);
    long long tot = (long long)N1 * 64;
    int nb = (int)std::min<long long>(2048, (tot + 255) / 256);
    long long ptot = (long long)N2 * 64;
    int pb = (int)std::min<long long>(2048, (ptot + 255) / 256);
    k_fillenc<<<pb, 256, 0, stream>>>((unsigned*)parena, ptot);
    hipMemsetAsync(cnt, 0, (size_t)N2 * 4, stream);
    k_pool<64><<<nb, 256, 0, stream>>>(harena, bnss, cl1, (unsigned*)parena, cnt, tot);
    k_dec<<<pb, 256, 0, stream>>>((unsigned*)parena, cnt, 6, ptot);
  }

  // ---- levels 2..4 ----
  run_level<64, 128, 2>(parena, N2, ei2, E2, ea2, W2, r2, b2, g2, be2, cl2, N3, 7,
                        harena, parena, degi, startb, cursor, perm, srcs, bas, bsum,
                        cnt, bnss, wth, wtl, pbuf, sbuf16, sbytes, stream);
  run_level<128, 256, 4>(parena, N3, ei3, E3, ea3, W3, r3, b3, g3, be3, cl3, N4, 8,
                         harena, parena, degi, startb, cursor, perm, srcs, bas, bsum,
                         cnt, bnss, wth, wtl, pbuf, sbuf16, sbytes, stream);
  run_level<256, 512, 8>(parena, N4, ei4, E4, ea4, W4, r4, b4, g4, be4, cl4, 512, 9,
                         harena, parena, degi, startb, cursor, perm, srcs, bas, bsum,
                         cnt, bnss, wth, wtl, pbuf, sbuf16, sbytes, stream);

  // ---- FC head ----
  hipMemsetAsync(fco, 0, 8 * 1024 * 4, stream);
  k_fc1p<<<dim3(16, 64), 256, 0, stream>>>(parena, fw1, fco);
  k_fc1fin<<<32, 256, 0, stream>>>(fco, fb1);
  k_fc2<<<8, 256, 0, stream>>>(fco, fw2, fb2, (float*)d_out);
}

// Round 19
// 1157.344 us; speedup vs baseline: 1.5240x; 1.5240x over previous
//
#include <hip/hip_runtime.h>
#include <hip/hip_bf16.h>
#include <cfloat>
#include <cmath>
#include <algorithm>

#define DEVI __device__ __forceinline__

typedef __attribute__((ext_vector_type(8))) short bf16x8;
typedef __attribute__((ext_vector_type(4))) float f32x4;

DEVI float eluf(float x){ return x > 0.f ? x : expm1f(x); }
DEVI unsigned encf(float v){ unsigned u = __float_as_uint(v); return (u & 0x80000000u) ? ~u : (u | 0x80000000u); }
DEVI float decf(unsigned u){ return (u & 0x80000000u) ? __uint_as_float(u & 0x7FFFFFFFu) : __uint_as_float(~u); }

DEVI unsigned short bfhi(float v){
  __hip_bfloat16 h = __float2bfloat16(v);
  return *reinterpret_cast<unsigned short*>(&h);
}
DEVI float bf2f(unsigned short u){
  __hip_bfloat16 h = *reinterpret_cast<__hip_bfloat16*>(&u);
  return __bfloat162float(h);
}

DEVI void basis3(const float* __restrict__ ea, int e, float fr[3], int k0[3]){
#pragma unroll
  for (int d = 0; d < 3; ++d){
    float p = ea[(size_t)e*3 + d];
    float v = fminf(fmaxf(p, 0.f), 1.f) * 2.f;
    float kf = fminf(floorf(v), 1.f);
    k0[d] = (int)kf;
    fr[d] = v - kf;
  }
}

// ---------------- CSR build ----------------
__global__ void k_degi(const int* __restrict__ ei, int E, int* __restrict__ deg){
  int e = blockIdx.x * 256 + threadIdx.x;
  if (e < E) atomicAdd(deg + ei[E + e], 1);
}

// parallel 3-phase exclusive scan over deg -> start/cursor (+ start[N])
__global__ __launch_bounds__(256) void k_scan1(const int* __restrict__ deg, int N, int* __restrict__ bsum){
  __shared__ int ls[256];
  const int t = threadIdx.x;
  const int base = blockIdx.x * 1024 + t * 4;
  int s = 0;
#pragma unroll
  for (int i = 0; i < 4; ++i){
    int idx = base + i;
    if (idx < N) s += deg[idx];
  }
  ls[t] = s;
  __syncthreads();
  for (int off = 128; off >= 1; off >>= 1){
    if (t < off) ls[t] += ls[t + off];
    __syncthreads();
  }
  if (t == 0) bsum[blockIdx.x] = ls[0];
}

__global__ __launch_bounds__(256) void k_scan2(int* __restrict__ bsum, int B1){
  __shared__ int ls[256];
  const int t = threadIdx.x;
  int v = (t < B1) ? bsum[t] : 0;
  ls[t] = v;
  __syncthreads();
  for (int off = 1; off < 256; off <<= 1){
    int u = (t >= off) ? ls[t - off] : 0;
    __syncthreads();
    ls[t] += u;
    __syncthreads();
  }
  if (t < B1) bsum[t] = ls[t] - v;   // exclusive
}

__global__ __launch_bounds__(256) void k_scan3(const int* __restrict__ deg, int N,
                                               const int* __restrict__ bsum,
                                               int* __restrict__ start, int* __restrict__ cursor){
  __shared__ int ls[256];
  const int t = threadIdx.x;
  const int base = blockIdx.x * 1024 + t * 4;
  int v[4]; int tsum = 0;
#pragma unroll
  for (int i = 0; i < 4; ++i){
    int idx = base + i;
    v[i] = (idx < N) ? deg[idx] : 0;
    tsum += v[i];
  }
  ls[t] = tsum;
  __syncthreads();
  for (int off = 1; off < 256; off <<= 1){
    int u = (t >= off) ? ls[t - off] : 0;
    __syncthreads();
    ls[t] += u;
    __syncthreads();
  }
  int run = bsum[blockIdx.x] + ls[t] - tsum;
#pragma unroll
  for (int i = 0; i < 4; ++i){
    int idx = base + i;
    if (idx < N){
      start[idx] = run; cursor[idx] = run;
      run += v[i];
      if (idx == N - 1) start[N] = run;
    }
  }
}

__global__ void k_perm(const int* __restrict__ ei, int E, int* __restrict__ cursor, int* __restrict__ perm){
  int e = blockIdx.x * 256 + threadIdx.x;
  if (e < E){
    int p = atomicAdd(cursor + ei[E + e], 1);
    perm[p] = e;
  }
}

// ---------------- phase A: per-edge separable basis vectors, stored in CSR order ----------------
__global__ void k_prep(const int* __restrict__ ei, const float* __restrict__ ea, int E,
                       const int* __restrict__ perm, int* __restrict__ srcs,
                       float4* __restrict__ bas){
  int j = blockIdx.x * 256 + threadIdx.x;
  if (j >= E) return;
  int e = perm[j];
  srcs[j] = ei[e];
  float fr[3]; int k0[3];
  basis3(ea, e, fr, k0);
#pragma unroll
  for (int d = 0; d < 3; ++d){
    bool z = (k0[d] == 0);
    float f = fr[d];
    bas[(size_t)j * 3 + d] = make_float4(z ? 1.f - f : 0.f,
                                         z ? f : 1.f - f,
                                         z ? 0.f : f, 0.f);
  }
}

// ---------------- phase B gather: dense rank-1 register accumulation, depth-4 pipeline ----------------
template<int FIN>
__global__ __launch_bounds__(256) void k_gather(
    const float* __restrict__ x, const int* __restrict__ start,
    const int* __restrict__ srcs, const float4* __restrict__ bas,
    unsigned short* __restrict__ Sh, int n0, int n1){
  constexpr int S = FIN / 64;
  constexpr int NPB = 4 / S;
  constexpr int KAUG = 28 * FIN;
  const int wv = threadIdx.x >> 6;
  const int lane = threadIdx.x & 63;
  const int n = n0 + blockIdx.x * NPB + wv / S;
  const int slice = wv % S;
  if (n >= n1) return;
  const int j0 = __builtin_amdgcn_readfirstlane(start[n]);
  const int j1 = __builtin_amdgcn_readfirstlane(start[n + 1]);
  const int off = slice * 64 + lane;

  float acc[27];
#pragma unroll
  for (int k = 0; k < 27; ++k) acc[k] = 0.f;

  auto ACC = [&](const float4& U, const float4& V, const float4& Wt, float xv){
    float ta[3] = {U.x * xv, U.y * xv, U.z * xv};
    float vb[3] = {V.x, V.y, V.z};
    float wc[3] = {Wt.x, Wt.y, Wt.z};
#pragma unroll
    for (int a = 0; a < 3; ++a)
#pragma unroll
      for (int b = 0; b < 3; ++b){
        float p = ta[a] * vb[b];
#pragma unroll
        for (int c = 0; c < 3; ++c)
          acc[(a * 3 + b) * 3 + c] = fmaf(p, wc[c], acc[(a * 3 + b) * 3 + c]);
      }
  };

  float4 U0, V0, W0, U1, V1, W1, U2, V2, W2, U3, V3, W3;
  float x0 = 0.f, xv1 = 0.f, x2 = 0.f, x3 = 0.f;
  if (j0 < j1){
    int ja = j0;
    int jb = min(j0 + 1, j1 - 1);
    int jc = min(j0 + 2, j1 - 1);
    int jd = min(j0 + 3, j1 - 1);
    U0 = bas[(size_t)ja * 3]; V0 = bas[(size_t)ja * 3 + 1]; W0 = bas[(size_t)ja * 3 + 2];
    x0 = x[(size_t)srcs[ja] * FIN + off];
    U1 = bas[(size_t)jb * 3]; V1 = bas[(size_t)jb * 3 + 1]; W1 = bas[(size_t)jb * 3 + 2];
    xv1 = x[(size_t)srcs[jb] * FIN + off];
    U2 = bas[(size_t)jc * 3]; V2 = bas[(size_t)jc * 3 + 1]; W2 = bas[(size_t)jc * 3 + 2];
    x2 = x[(size_t)srcs[jc] * FIN + off];
    U3 = bas[(size_t)jd * 3]; V3 = bas[(size_t)jd * 3 + 1]; W3 = bas[(size_t)jd * 3 + 2];
    x3 = x[(size_t)srcs[jd] * FIN + off];
  }
  int j = j0;
  for (; j + 3 < j1; j += 4){
    int ja = min(j + 4, j1 - 1);
    int jb = min(j + 5, j1 - 1);
    int jc = min(j + 6, j1 - 1);
    int jd = min(j + 7, j1 - 1);
    float4 Ua = bas[(size_t)ja * 3], Va = bas[(size_t)ja * 3 + 1], Wa = bas[(size_t)ja * 3 + 2];
    float xa = x[(size_t)srcs[ja] * FIN + off];
    float4 Ub = bas[(size_t)jb * 3], Vb = bas[(size_t)jb * 3 + 1], Wb = bas[(size_t)jb * 3 + 2];
    float xb = x[(size_t)srcs[jb] * FIN + off];
    float4 Uc = bas[(size_t)jc * 3], Vc = bas[(size_t)jc * 3 + 1], Wc = bas[(size_t)jc * 3 + 2];
    float xc = x[(size_t)srcs[jc] * FIN + off];
    float4 Ud = bas[(size_t)jd * 3], Vd = bas[(size_t)jd * 3 + 1], Wd = bas[(size_t)jd * 3 + 2];
    float xd = x[(size_t)srcs[jd] * FIN + off];
    ACC(U0, V0, W0, x0);
    ACC(U1, V1, W1, xv1);
    ACC(U2, V2, W2, x2);
    ACC(U3, V3, W3, x3);
    U0 = Ua; V0 = Va; W0 = Wa; x0 = xa;
    U1 = Ub; V1 = Vb; W1 = Wb; xv1 = xb;
    U2 = Uc; V2 = Vc; W2 = Wc; x2 = xc;
    U3 = Ud; V3 = Vd; W3 = Wd; x3 = xd;
  }
  if (j < j1)     ACC(U0, V0, W0, x0);
  if (j + 1 < j1) ACC(U1, V1, W1, xv1);
  if (j + 2 < j1) ACC(U2, V2, W2, x2);

  const float invd = 1.f / fmaxf((float)(j1 - j0), 1.f);
  const size_t rb = (size_t)(n - n0) * KAUG + off;
#pragma unroll
  for (int k = 0; k < 27; ++k)
    Sh[rb + (size_t)k * FIN] = bfhi(acc[k] * invd);
  Sh[rb + (size_t)27 * FIN] = bfhi(x[(size_t)n * FIN + off]);
}

// ---------------- W conversion: W_aug^T -> bf16 hi/lo [FOUT][KAUG] (tiled transpose) ----------------
template<int FIN, int FOUT>
__global__ __launch_bounds__(256) void k_cvtW(const float* __restrict__ W, const float* __restrict__ root,
                                              unsigned short* __restrict__ wh, unsigned short* __restrict__ wl){
  constexpr int KA = 28 * FIN;
  __shared__ unsigned short th[64][66];
  __shared__ unsigned short tl[64][66];
  const int kk0 = blockIdx.x * 64, o0 = blockIdx.y * 64;
  const int tx = threadIdx.x & 63, ty = threadIdx.x >> 6;
  for (int i = ty; i < 64; i += 4){
    int kk = kk0 + i;
    float v = (kk < 27 * FIN) ? W[(size_t)kk * FOUT + o0 + tx]
                              : root[(size_t)(kk - 27 * FIN) * FOUT + o0 + tx];
    unsigned short h = bfhi(v);
    th[i][tx] = h;
    tl[i][tx] = bfhi(v - bf2f(h));
  }
  __syncthreads();
  for (int i = ty; i < 64; i += 4){
    wh[(size_t)(o0 + i) * KA + kk0 + tx] = th[tx][i];
    wl[(size_t)(o0 + i) * KA + kk0 + tx] = tl[tx][i];
  }
}

// ---------------- split-K MFMA conv GEMM, BM=128 x BN=128: P[z] = S @ (Wh + Wl) ----------------
template<int KAUG, int FOUT, int KS>
__global__ __launch_bounds__(256) void k_mfmaconv(
    const unsigned short* __restrict__ Sh,
    const unsigned short* __restrict__ Wh, const unsigned short* __restrict__ Wl,
    float* __restrict__ P, int cn){
  constexpr int KSTEPS = KAUG / 32 / KS;
  __shared__ unsigned short Ah[128][40];
  __shared__ unsigned short Bh[128][40];
  __shared__ unsigned short Bl[128][40];
  const int t = threadIdx.x;
  const int lane = t & 63, wv = t >> 6;
  const int wm = (wv >> 1) * 64, wn = (wv & 1) * 64;
  const int mb = blockIdx.y * 128;
  const int ob = blockIdx.x * 128;
  const int kbase = blockIdx.z * KSTEPS * 32;
  const int l16 = lane & 15, l4 = lane >> 4;
  f32x4 acc[4][4] = {};

  for (int ks = 0; ks < KSTEPS; ++ks){
#pragma unroll
    for (int i = 0; i < 2; ++i){
      int slot = t + i * 256;
      int row = slot >> 2, col = (slot & 3) * 8;
      uint4 va = make_uint4(0, 0, 0, 0);
      if (mb + row < cn)
        va = *reinterpret_cast<const uint4*>(Sh + (size_t)(mb + row) * KAUG + kbase + ks * 32 + col);
      *reinterpret_cast<uint4*>(&Ah[row][col]) = va;
      *reinterpret_cast<uint4*>(&Bh[row][col]) =
        *reinterpret_cast<const uint4*>(Wh + (size_t)(ob + row) * KAUG + kbase + ks * 32 + col);
      *reinterpret_cast<uint4*>(&Bl[row][col]) =
        *reinterpret_cast<const uint4*>(Wl + (size_t)(ob + row) * KAUG + kbase + ks * 32 + col);
    }
    __syncthreads();
    bf16x8 ah[4], bh[4], bl[4];
#pragma unroll
    for (int m = 0; m < 4; ++m)
      ah[m] = *reinterpret_cast<const bf16x8*>(&Ah[wm + m * 16 + l16][l4 * 8]);
#pragma unroll
    for (int n = 0; n < 4; ++n){
      bh[n] = *reinterpret_cast<const bf16x8*>(&Bh[wn + n * 16 + l16][l4 * 8]);
      bl[n] = *reinterpret_cast<const bf16x8*>(&Bl[wn + n * 16 + l16][l4 * 8]);
    }
#pragma unroll
    for (int m = 0; m < 4; ++m)
#pragma unroll
      for (int n = 0; n < 4; ++n){
        acc[m][n] = __builtin_amdgcn_mfma_f32_16x16x32_bf16(ah[m], bh[n], acc[m][n], 0, 0, 0);
        acc[m][n] = __builtin_amdgcn_mfma_f32_16x16x32_bf16(ah[m], bl[n], acc[m][n], 0, 0, 0);
      }
    __syncthreads();
  }
  float* Pz = P + (size_t)blockIdx.z * cn * FOUT;
#pragma unroll
  for (int n = 0; n < 4; ++n){
    int col = ob + wn + n * 16 + l16;
#pragma unroll
    for (int m = 0; m < 4; ++m){
#pragma unroll
      for (int r = 0; r < 4; ++r){
        int gr = mb + wm + m * 16 + l4 * 4 + r;
        if (gr < cn) Pz[(size_t)gr * FOUT + col] = acc[m][n][r];
      }
    }
  }
}

// ---------------- split-K reduce + bias + elu ----------------
template<int FOUT, int KS>
__global__ __launch_bounds__(256) void k_red(const float* __restrict__ P, const float* __restrict__ bias,
                                             float* __restrict__ H, int cn, int n0){
  const size_t tot4 = (size_t)cn * FOUT / 4;
  const size_t zs = tot4;
  float* Hb = H + (size_t)n0 * FOUT;
  for (size_t i = (size_t)blockIdx.x * 256 + threadIdx.x; i < tot4; i += (size_t)gridDim.x * 256){
    f32x4 s = reinterpret_cast<const f32x4*>(P)[i];
#pragma unroll
    for (int z = 1; z < KS; ++z){
      f32x4 v = reinterpret_cast<const f32x4*>(P)[(size_t)z * zs + i];
      s[0] += v[0]; s[1] += v[1]; s[2] += v[2]; s[3] += v[3];
    }
    int col = (int)((i * 4) % FOUT);
    float4 b = *reinterpret_cast<const float4*>(bias + col);
    f32x4 o;
    o[0] = eluf(s[0] + b.x); o[1] = eluf(s[1] + b.y);
    o[2] = eluf(s[2] + b.z); o[3] = eluf(s[3] + b.w);
    reinterpret_cast<f32x4*>(Hb)[i] = o;
  }
}

// ---------------- fused level-1 (Fin=1, deg==8, dst sorted by construction) ----------------
__global__ __launch_bounds__(256) void k_l1(const int* __restrict__ ei, const float* __restrict__ ea,
    const float* __restrict__ x, const float* __restrict__ W, const float* __restrict__ root,
    const float* __restrict__ bias, float* __restrict__ H){
  __shared__ float sl[256 * 27];
  const int t = threadIdx.x;
  const int nb = blockIdx.x * 256;
  const int n = nb + t;
  float acc[27];
#pragma unroll
  for (int k = 0; k < 27; ++k) acc[k] = 0.f;
  for (int j = 0; j < 8; ++j){
    int e = n * 8 + j;
    int src = ei[e];
    float fr[3]; int k0[3];
    basis3(ea, e, fr, k0);
    float xv = x[src];
    float u[3][3];
#pragma unroll
    for (int d = 0; d < 3; ++d){
      bool z = (k0[d] == 0);
      float f = fr[d];
      u[d][0] = z ? 1.f - f : 0.f;
      u[d][1] = z ? f : 1.f - f;
      u[d][2] = z ? 0.f : f;
    }
    float ta[3] = {u[0][0] * xv, u[0][1] * xv, u[0][2] * xv};
#pragma unroll
    for (int a = 0; a < 3; ++a)
#pragma unroll
      for (int b = 0; b < 3; ++b){
        float p = ta[a] * u[1][b];
#pragma unroll
        for (int c = 0; c < 3; ++c)
          acc[(a * 3 + b) * 3 + c] = fmaf(p, u[2][c], acc[(a * 3 + b) * 3 + c]);
      }
  }
#pragma unroll
  for (int k = 0; k < 27; ++k) sl[t * 27 + k] = acc[k];
  const int o = t & 63, grp = t >> 6;
  float wr[27];
#pragma unroll
  for (int k = 0; k < 27; ++k) wr[k] = W[k * 64 + o];
  const float ro = root[o], bo = bias[o];
  __syncthreads();
  for (int r = 0; r < 64; ++r){
    int m = grp * 64 + r;
    float a = 0.f;
#pragma unroll
    for (int k = 0; k < 27; ++k) a = fmaf(sl[m * 27 + k], wr[k], a);
    H[(size_t)(nb + m) * 64 + o] = eluf(a * 0.125f + x[nb + m] * ro + bo);
  }
}

// ---------------- BN stats: two-stage, register accumulation, no atomics ----------------
template<int F>
__global__ __launch_bounds__(256) void k_bnstat(const float* __restrict__ h, int N, float* __restrict__ partial){
  constexpr int FE = (F < 256) ? F : 256;
  constexpr int TPC = 256 / FE;
  constexpr int CPT = (F > 256) ? (F / 256) : 1;
  constexpr int LOGFE = (FE == 64) ? 6 : (FE == 128) ? 7 : 8;
  const int t = threadIdx.x;
  const int col = t & (FE - 1);
  const int ro = t >> LOGFE;
  float s[CPT], q[CPT];
#pragma unroll
  for (int c = 0; c < CPT; ++c){ s[c] = 0.f; q[c] = 0.f; }
  for (int r = blockIdx.x * TPC + ro; r < N; r += gridDim.x * TPC){
#pragma unroll
    for (int c = 0; c < CPT; ++c){
      float v = h[(size_t)r * F + col + c * 256];
      s[c] += v; q[c] += v * v;
    }
  }
  float* pb = partial + (size_t)blockIdx.x * 2 * F;
  __shared__ float ls[2 * FE];
  if (TPC == 1){
#pragma unroll
    for (int c = 0; c < CPT; ++c){
      pb[col + c * 256] = s[c];
      pb[F + col + c * 256] = q[c];
    }
  } else {
    for (int p = 0; p < TPC; ++p){
      if (ro == p){
        if (p == 0){ ls[col] = s[0]; ls[FE + col] = q[0]; }
        else { ls[col] += s[0]; ls[FE + col] += q[0]; }
      }
      __syncthreads();
    }
    if (t < 2 * F) pb[t] = ls[t];
  }
}

__global__ void k_bnfin2(const float* __restrict__ partial, int G, const float* __restrict__ gamma,
                         const float* __restrict__ beta, float invn, int F, float* __restrict__ ss){
  int f = blockIdx.x * 256 + threadIdx.x;
  if (f >= F) return;
  float s = 0.f, q = 0.f;
  for (int g = 0; g < G; ++g){
    s += partial[(size_t)g * 2 * F + f];
    q += partial[(size_t)g * 2 * F + F + f];
  }
  float mu = s * invn;
  float var = q * invn - mu * mu;
  float sc = gamma[f] * rsqrtf(var + 1e-5f);
  ss[f] = sc;
  ss[F + f] = beta[f] - mu * sc;
}

__global__ void k_fillenc(unsigned* __restrict__ p, long long n){
  for (long long i = (long long)blockIdx.x * 256 + threadIdx.x; i < n; i += (long long)gridDim.x * 256)
    p[i] = 0x00800000u;
}

template<int F>
__global__ __launch_bounds__(256) void k_pool(const float* __restrict__ h, const float* __restrict__ ss,
                     const int* __restrict__ cl, unsigned* __restrict__ enc,
                     int* __restrict__ cnt, long long total){
  constexpr int LOG = (F == 64) ? 6 : (F == 128) ? 7 : (F == 256) ? 8 : 9;
  for (long long idx = (long long)blockIdx.x * 256 + threadIdx.x; idx < total; idx += (long long)gridDim.x * 256){
    int f = (int)(idx & (F - 1));
    int m = (int)(idx >> LOG);
    int c = cl[m];
    float v = fmaf(h[idx], ss[f], ss[F + f]);
    atomicMax(enc + (size_t)c * F + f, encf(v));
    if (f == 0) atomicAdd(cnt + c, 1);
  }
}

__global__ void k_dec(unsigned* __restrict__ enc, const int* __restrict__ cnt, int logF, long long total){
  for (long long idx = (long long)blockIdx.x * 256 + threadIdx.x; idx < total; idx += (long long)gridDim.x * 256){
    int sg = (int)(idx >> logF);
    float v = (cnt[sg] > 0) ? decf(enc[idx]) : 0.f;
    reinterpret_cast<float*>(enc)[idx] = v;
  }
}

// ---------------- FC head ----------------
__global__ __launch_bounds__(256) void k_fc1p(const float* __restrict__ X, const float* __restrict__ Wt,
                       float* __restrict__ outacc){
  __shared__ float Xs[8][512];
  __shared__ float4 red[16][16];
  const int t = threadIdx.x;
  const int o0 = blockIdx.x * 64;
  const int kbase = blockIdx.y * 512;
  for (int i = t; i < 8 * 128; i += 256){
    int g = i >> 7, u = i & 127;
    reinterpret_cast<float4*>(Xs[g])[u] =
      *reinterpret_cast<const float4*>(X + (size_t)g * 32768 + kbase + u * 4);
  }
  __syncthreads();
  const int ol = t & 15;
  const int kr = t >> 4;
  float4 acc[8];
#pragma unroll
  for (int g = 0; g < 8; ++g) acc[g] = make_float4(0.f, 0.f, 0.f, 0.f);
#pragma unroll 4
  for (int kk = kr; kk < 512; kk += 16){
    float4 wv = *reinterpret_cast<const float4*>(Wt + (size_t)(kbase + kk) * 1024 + o0 + ol * 4);
#pragma unroll
    for (int g = 0; g < 8; ++g){
      float xv = Xs[g][kk];
      acc[g].x = fmaf(xv, wv.x, acc[g].x);
      acc[g].y = fmaf(xv, wv.y, acc[g].y);
      acc[g].z = fmaf(xv, wv.z, acc[g].z);
      acc[g].w = fmaf(xv, wv.w, acc[g].w);
    }
  }
  for (int g = 0; g < 8; ++g){
    red[kr][ol] = acc[g];
    __syncthreads();
    if (kr == 0){
      float4 s = red[0][ol];
#pragma unroll
      for (int p = 1; p < 16; ++p){
        float4 v = red[p][ol];
        s.x += v.x; s.y += v.y; s.z += v.z; s.w += v.w;
      }
      atomicAdd(&outacc[(size_t)g * 1024 + o0 + ol * 4 + 0], s.x);
      atomicAdd(&outacc[(size_t)g * 1024 + o0 + ol * 4 + 1], s.y);
      atomicAdd(&outacc[(size_t)g * 1024 + o0 + ol * 4 + 2], s.z);
      atomicAdd(&outacc[(size_t)g * 1024 + o0 + ol * 4 + 3], s.w);
    }
    __syncthreads();
  }
}

__global__ void k_fc1fin(float* __restrict__ o, const float* __restrict__ b){
  int i = blockIdx.x * 256 + threadIdx.x;
  if (i < 8192) o[i] = eluf(o[i] + b[i & 1023]);
}

__global__ __launch_bounds__(256) void k_fc2(const float* __restrict__ h, const float* __restrict__ W2,
                      const float* __restrict__ b2, float* __restrict__ out){
  const int g = blockIdx.x;
  const int o = threadIdx.x & 1;
  const int kk = threadIdx.x >> 1;
  float acc = 0.f;
  for (int k = kk; k < 1024; k += 128) acc = fmaf(h[(size_t)g * 1024 + k], W2[(size_t)k * 2 + o], acc);
  __shared__ float ls[256];
  ls[threadIdx.x] = acc;
  __syncthreads();
  for (int st = 64; st >= 1; st >>= 1){
    if (kk < st) ls[kk * 2 + o] += ls[(kk + st) * 2 + o];
    __syncthreads();
  }
  if (kk == 0) out[g * 2 + o] = ls[o] + b2[o];
}

// ---------------- per-level driver ----------------
template<int FIN, int FOUT, int KS>
static void run_level(const float* xin, int N, const int* ei, int E, const float* ea,
                      const float* W, const float* root, const float* bias,
                      const float* gamma, const float* beta,
                      const int* cl, int npool, int logF,
                      float* h, float* pout, int* degi, int* startb, int* cursor, int* perm,
                      int* srcs, float4* bas, int* bsum,
                      int* cnt, float* bnss,
                      unsigned short* wth, unsigned short* wtl, float* pbuf,
                      unsigned short* sbuf16, size_t sbytes, hipStream_t stream){
  constexpr int KAUG = 28 * FIN;
  hipMemsetAsync(degi, 0, (size_t)N * 4, stream);
  k_degi<<<(E + 255) / 256, 256, 0, stream>>>(ei, E, degi);
  int B1 = (N + 1023) / 1024;
  k_scan1<<<B1, 256, 0, stream>>>(degi, N, bsum);
  k_scan2<<<1, 256, 0, stream>>>(bsum, B1);
  k_scan3<<<B1, 256, 0, stream>>>(degi, N, bsum, startb, cursor);
  k_perm<<<(E + 255) / 256, 256, 0, stream>>>(ei, E, cursor, perm);
  k_prep<<<(E + 255) / 256, 256, 0, stream>>>(ei, ea, E, perm, srcs, bas);
  k_cvtW<FIN, FOUT><<<dim3(KAUG / 64, FOUT / 64), 256, 0, stream>>>(W, root, wth, wtl);
  const size_t perNode = (size_t)KAUG * 2;   // hi plane only, 2B
  long long cN = (long long)(sbytes / perNode);
  int chunk = (int)std::min<long long>((long long)N, std::max<long long>(cN, 1));
  constexpr int NPB = 256 / FIN;
  unsigned short* Sh = sbuf16;
  for (int n0 = 0; n0 < N; n0 += chunk){
    int n1e = std::min(N, n0 + chunk);
    int cn = n1e - n0;
    k_gather<FIN><<<(cn + NPB - 1) / NPB, 256, 0, stream>>>(xin, startb, srcs, bas, Sh, n0, n1e);
    dim3 g(FOUT / 128, (cn + 127) / 128, KS);
    k_mfmaconv<KAUG, FOUT, KS><<<g, 256, 0, stream>>>(Sh, wth, wtl, pbuf, cn);
    int rb = (int)std::min<long long>(2048, ((long long)cn * FOUT / 4 + 255) / 256);
    k_red<FOUT, KS><<<rb, 256, 0, stream>>>(pbuf, bias, h, cn, n0);
  }
  k_bnstat<FOUT><<<256, 256, 0, stream>>>(h, N, pbuf);
  k_bnfin2<<<(FOUT + 255) / 256, 256, 0, stream>>>(pbuf, 256, gamma, beta, 1.f / (float)N, FOUT, bnss);
  long long tot = (long long)N * FOUT;
  int nb = (int)std::min<long long>(2048, (tot + 255) / 256);
  long long ptot = (long long)npool * FOUT;
  int pb = (int)std::min<long long>(2048, (ptot + 255) / 256);
  k_fillenc<<<pb, 256, 0, stream>>>((unsigned*)pout, ptot);
  hipMemsetAsync(cnt, 0, (size_t)npool * 4, stream);
  k_pool<FOUT><<<nb, 256, 0, stream>>>(h, bnss, cl, (unsigned*)pout, cnt, tot);
  k_dec<<<pb, 256, 0, stream>>>((unsigned*)pout, cnt, logF, ptot);
}

extern "C" void kernel_launch(void* const* d_in, const int* in_sizes, int n_in,
                              void* d_out, int out_size, void* d_ws, size_t ws_size,
                              hipStream_t stream){
  const float* x1  = (const float*)d_in[0];
  const int*   ei1 = (const int*)d_in[1];
  const float* ea1 = (const float*)d_in[2];
  const int*   cl1 = (const int*)d_in[3];
  const int*   ei2 = (const int*)d_in[4];
  const float* ea2 = (const float*)d_in[5];
  const int*   cl2 = (const int*)d_in[6];
  const int*   ei3 = (const int*)d_in[7];
  const float* ea3 = (const float*)d_in[8];
  const int*   cl3 = (const int*)d_in[9];
  const int*   ei4 = (const int*)d_in[10];
  const float* ea4 = (const float*)d_in[11];
  const int*   cl4 = (const int*)d_in[12];
  const float* W1 = (const float*)d_in[13]; const float* r1 = (const float*)d_in[14];
  const float* b1 = (const float*)d_in[15]; const float* g1 = (const float*)d_in[16]; const float* be1 = (const float*)d_in[17];
  const float* W2 = (const float*)d_in[18]; const float* r2 = (const float*)d_in[19];
  const float* b2 = (const float*)d_in[20]; const float* g2 = (const float*)d_in[21]; const float* be2 = (const float*)d_in[22];
  const float* W3 = (const float*)d_in[23]; const float* r3 = (const float*)d_in[24];
  const float* b3 = (const float*)d_in[25]; const float* g3 = (const float*)d_in[26]; const float* be3 = (const float*)d_in[27];
  const float* W4 = (const float*)d_in[28]; const float* r4 = (const float*)d_in[29];
  const float* b4 = (const float*)d_in[30]; const float* g4 = (const float*)d_in[31]; const float* be4 = (const float*)d_in[32];
  const float* fw1 = (const float*)d_in[33]; const float* fb1 = (const float*)d_in[34];
  const float* fw2 = (const float*)d_in[35]; const float* fb2 = (const float*)d_in[36];

  const int N1 = in_sizes[0];
  const int E1 = in_sizes[1] / 2;
  const int N2 = in_sizes[6];
  const int E2 = in_sizes[4] / 2;
  const int N3 = in_sizes[9];
  const int E3 = in_sizes[7] / 2;
  const int N4 = in_sizes[12];
  const int E4 = in_sizes[10] / 2;
  (void)E1;

  char* base = (char*)d_ws;
  size_t off = 0;
  auto alloc = [&](size_t bytes) -> char* {
    char* p = base + off;
    off += (bytes + 255) & ~(size_t)255;
    return p;
  };
  size_t hbytes = 4 * std::max(std::max((size_t)N1 * 64, (size_t)N2 * 128),
                               std::max((size_t)N3 * 256, (size_t)N4 * 512));
  size_t pbytes = 4 * std::max(std::max((size_t)N2 * 64, (size_t)N3 * 128),
                               std::max((size_t)N4 * 256, (size_t)512 * 512));
  float* harena = (float*)alloc(hbytes);
  float* parena = (float*)alloc(pbytes);
  float* fco = (float*)alloc(8 * 1024 * 4);
  int Nmax = std::max(std::max(N1, N2), std::max(N3, N4));
  int Emax = std::max(std::max(E2, E3), E4);
  int* degi = (int*)alloc((size_t)Nmax * 4);
  int* startb = (int*)alloc(((size_t)Nmax + 1) * 4);
  int* cursor = (int*)alloc((size_t)Nmax * 4);
  int* perm = (int*)alloc((size_t)Emax * 4);
  int* srcs = (int*)alloc((size_t)Emax * 4);
  float4* bas = (float4*)alloc((size_t)Emax * 48);
  int* bsum = (int*)alloc(256 * 4);
  int* cnt = (int*)alloc((size_t)std::max(std::max(N2, N3), std::max(N4, 512)) * 4);
  float* bnss = (float*)alloc(2 * 512 * 4);
  unsigned short* wth = (unsigned short*)alloc((size_t)512 * 7168 * 2);
  unsigned short* wtl = (unsigned short*)alloc((size_t)512 * 7168 * 2);
  size_t pmax = std::max((size_t)2 * N2 * 128, std::max((size_t)4 * N3 * 256, (size_t)8 * N4 * 512));
  pmax = std::max(pmax, (size_t)256 * 2 * 512);   // bnstat partials
  float* pbuf = (float*)alloc(pmax * 4);
  unsigned short* sbuf16 = (unsigned short*)(base + off);
  size_t sbytes = ws_size > off ? ws_size - off : 0;

  // ---- level 1 (fused; Fin=1, deg==8, dst sorted by construction) ----
  {
    k_l1<<<N1 / 256, 256, 0, stream>>>(ei1, ea1, x1, W1, r1, b1, harena);
    k_bnstat<64><<<256, 256, 0, stream>>>(harena, N1, pbuf);
    k_bnfin2<<<1, 256, 0, stream>>>(pbuf, 256, g1, be1, 1.f / (float)N1, 64, bnss);
    long long tot = (long long)N1 * 64;
    int nb = (int)std::min<long long>(2048, (tot + 255) / 256);
    long long ptot = (long long)N2 * 64;
    int pb = (int)std::min<long long>(2048, (ptot + 255) / 256);
    k_fillenc<<<pb, 256, 0, stream>>>((unsigned*)parena, ptot);
    hipMemsetAsync(cnt, 0, (size_t)N2 * 4, stream);
    k_pool<64><<<nb, 256, 0, stream>>>(harena, bnss, cl1, (unsigned*)parena, cnt, tot);
    k_dec<<<pb, 256, 0, stream>>>((unsigned*)parena, cnt, 6, ptot);
  }

  // ---- levels 2..4 ----
  run_level<64, 128, 2>(parena, N2, ei2, E2, ea2, W2, r2, b2, g2, be2, cl2, N3, 7,
                        harena, parena, degi, startb, cursor, perm, srcs, bas, bsum,
                        cnt, bnss, wth, wtl, pbuf, sbuf16, sbytes, stream);
  run_level<128, 256, 4>(parena, N3, ei3, E3, ea3, W3, r3, b3, g3, be3, cl3, N4, 8,
                         harena, parena, degi, startb, cursor, perm, srcs, bas, bsum,
                         cnt, bnss, wth, wtl, pbuf, sbuf16, sbytes, stream);
  run_level<256, 512, 8>(parena, N4, ei4, E4, ea4, W4, r4, b4, g4, be4, cl4, 512, 9,
                         harena, parena, degi, startb, cursor, perm, srcs, bas, bsum,
                         cnt, bnss, wth, wtl, pbuf, sbuf16, sbytes, stream);

  // ---- FC head ----
  hipMemsetAsync(fco, 0, 8 * 1024 * 4, stream);
  k_fc1p<<<dim3(16, 64), 256, 0, stream>>>(parena, fw1, fco);
  k_fc1fin<<<32, 256, 0, stream>>>(fco, fb1);
  k_fc2<<<8, 256, 0, stream>>>(fco, fw2, fb2, (float*)d_out);
}